// Round 12
// baseline (125.978 us; speedup 1.0000x reference)
//
#include <hip/hip_runtime.h>
#include <stdint.h>

#define E_DIM 512
#define L_IN  4096
#define L_OUT 4092   // L_IN - KW + 1
#define KW    5
#define B_DIM 8
#define L2P   4096   // padded row stride for y workspace
#define L_DS  2048   // downsampled output length
#define LP    4160   // padded length for transposed x

typedef __attribute__((ext_vector_type(8))) short short8;
typedef __attribute__((ext_vector_type(4))) float f32x4;

__device__ __forceinline__ unsigned short f2bf(float f) {
    uint32_t u = __float_as_uint(f);
    u += 0x7fffu + ((u >> 16) & 1);   // round-to-nearest-even
    return (unsigned short)(u >> 16);
}
__device__ __forceinline__ float bf2f(unsigned short h) {
    return __uint_as_float((uint32_t)h << 16);
}
__device__ __forceinline__ int mod3(int v) {   // v in [0,8]
    if (v >= 6) v -= 6;
    if (v >= 3) v -= 3;
    return v;
}

// ---------------------------------------------------------------------------
// Converter 1: x [B][E][4096] f32 -> Xt [B][LP][E] bf16 (transposed; l-rows
// >= 4096 zeroed). f32 LDS tile [64][65] (2-way banks = free).
// ---------------------------------------------------------------------------
__global__ __launch_bounds__(256)
void xt_kernel(const float* __restrict__ x, unsigned short* __restrict__ Xt)
{
    const int b  = blockIdx.z;
    const int i0 = blockIdx.y * 64;
    const int l0 = blockIdx.x * 64;
    __shared__ float T[64][65];
    const int tid = threadIdx.x;

    const int ir = tid >> 4;          // 0..15
    const int cq = (tid & 15) * 4;    // 0..60
    #pragma unroll
    for (int jj = 0; jj < 4; ++jj) {
        int i = jj * 16 + ir;
        float4 v = make_float4(0.f, 0.f, 0.f, 0.f);
        if (l0 < L_IN)
            v = *reinterpret_cast<const float4*>(
                &x[((size_t)b * E_DIM + i0 + i) * L_IN + l0 + cq]);
        T[i][cq + 0] = v.x; T[i][cq + 1] = v.y;
        T[i][cq + 2] = v.z; T[i][cq + 3] = v.w;
    }
    __syncthreads();
    const int h  = tid & 31;          // i-pair
    const int rq = tid >> 5;          // 0..7
    #pragma unroll
    for (int j = 0; j < 8; ++j) {
        int lr = j * 8 + rq;
        ushort2 o;
        o.x = f2bf(T[2 * h][lr]);
        o.y = f2bf(T[2 * h + 1][lr]);
        *reinterpret_cast<ushort2*>(
            &Xt[((size_t)b * LP + l0 + lr) * E_DIM + i0 + 2 * h]) = o;
    }
}

// ---------------------------------------------------------------------------
// Converter 2: w [E][E][5] f32 -> Wt [5][E][E] bf16  (Wt[k][e][i] = w[e][i][k])
// ---------------------------------------------------------------------------
__global__ __launch_bounds__(256)
void wt_kernel(const float* __restrict__ w, unsigned short* __restrict__ Wt)
{
    int idx = blockIdx.x * 256 + threadIdx.x;   // e*512 + i
    if (idx >= E_DIM * E_DIM) return;
    #pragma unroll
    for (int k = 0; k < KW; ++k)
        Wt[(size_t)k * E_DIM * E_DIM + idx] = f2bf(w[(size_t)idx * KW + k]);
}

// ---------------------------------------------------------------------------
// Kernel 1: implicit-GEMM conv via MFMA (+ fused score partials).
// y[b,e,l] = sum_k sum_i Wt[k][e][i] * Xt[b][l+k][i] + bias[e]   (bf16 out)
//
// OCCUPANCY-FIRST redesign: 3 independent blocks/CU (the m97/m114 overlap
// mechanism we were missing at 2 blocks/CU).
//   Block 128e x 128l, 4 waves (2x2), wave 64e x 64l -> acc 4x4 = 64 AGPR.
//   __launch_bounds__(256,3) caps total regs at 170 -> 3 waves/SIMD.
//   LDS 42 KB: X double-buffer (2 x 9 KB) + W tap-slice ring-3 (3 x 8 KB)
//   -> 3 blocks/CU co-resident, mutually async -> LDS/MFMA pipes co-run.
// Per K-step (BK=32): 5 phases (one tap each):
//   [8 ds_read (A slice slot, B X-buf)] [stage: W slice g+2; X parts at
//   kt=0,1] [counted vmcnt = own issues] [barrier] [setprio 16 MFMA] [barrier]
// vmcnt is NEVER 0 mid-loop and never forces same-phase issues (R6 bug fix):
// W slices have a 2-phase deadline, X a 4-phase deadline.
// XOR swizzle f(row)=(row>>1)&3 on the 16B slot: conflict-free (R4-verified).
// ---------------------------------------------------------------------------
#define XB_ROWS  144                          // 128 l + 4 halo, rounded to 16
#define XB_BYTES (XB_ROWS * 64)               // 9216
#define WOFF     (2 * XB_BYTES)               // 18432
#define WSL      8192                         // one W slice: 128e x 32i bf16
#define LDS_BYTES (WOFF + 3 * WSL)            // 43008

__global__ __launch_bounds__(256, 3)
void conv_mfma(const unsigned short* __restrict__ Xt,
               const unsigned short* __restrict__ Wt,
               const float* __restrict__ bias,
               const float* __restrict__ sw,
               unsigned short* __restrict__ y,
               float* __restrict__ sp)
{
    __shared__ __align__(16) unsigned char lds[LDS_BYTES];
    const int l0 = blockIdx.x * 128;
    const int e0 = blockIdx.y * 128;
    const int b  = blockIdx.z;
    const int tid  = threadIdx.x;
    const int lane = tid & 63;
    const int wv   = tid >> 6;
    const int wr = wv >> 1, wc = wv & 1;      // e-half / l-half of 128x128
    const int lr = lane & 15, lg = lane >> 4; // frag row / k-group
    const int ln4r = lane >> 2;               // row within 1KB chunk
    const int xswz = ((lane & 3) ^ ((lane >> 3) & 3)) * 8;   // stage-side swz
    const int swz  = (lg ^ ((lr >> 1) & 3)) << 4;            // read-side swz

    const unsigned short* xt_base =
        Xt + ((size_t)b * LP + l0) * E_DIM + xswz;

    auto stageW = [&](int slot, int tap, int i0) {
        for (int c = wv; c < 8; c += 4) {           // 2 chunks per wave
            int er = c * 16 + ln4r;                 // e_rel in [0,128)
            const unsigned short* gp =
                Wt + ((size_t)tap * E_DIM + e0 + er) * E_DIM + i0 + xswz;
            __builtin_amdgcn_global_load_lds(
                (const __attribute__((address_space(1))) void*)gp,
                (__attribute__((address_space(3))) void*)(lds + WOFF + slot * WSL + c * 1024),
                16, 0, 0);
        }
    };
    auto stageX1 = [&](int buf, int i0, int cch) {  // one 1KB chunk
        int row = cch * 16 + ln4r;                  // l_rel in [0,144)
        const unsigned short* gp = xt_base + (size_t)row * E_DIM + i0;
        __builtin_amdgcn_global_load_lds(
            (const __attribute__((address_space(1))) void*)gp,
            (__attribute__((address_space(3))) void*)(lds + buf * XB_BYTES + cch * 1024),
            16, 0, 0);
    };

    f32x4 acc[4][4] = {};

    // prologue: X(step0) all 9 chunks + W slices g=0,1 (slots 0,1); drain.
    stageX1(0, 0, wv); stageX1(0, 0, wv + 4);
    if (wv == 0) stageX1(0, 0, 8);
    stageW(0, 0, 0);
    stageW(1, 1, 0);
    asm volatile("s_waitcnt vmcnt(0)" ::: "memory");
    __builtin_amdgcn_s_barrier();

    int s0 = 0;                                    // (5*ks) % 3
    for (int ks = 0; ks < 16; ++ks) {
        const int par  = ks & 1;
        const int xoff = par * XB_BYTES;
        const int i0n  = (ks + 1) * 32;
        const bool more = (ks < 15);
        #pragma unroll
        for (int kt = 0; kt < KW; ++kt) {
            // 1) fragment reads (slot g staged 2 phases ago, barrier-published)
            const int slot = mod3(s0 + kt);
            short8 aF[4], bF[4];
            #pragma unroll
            for (int m = 0; m < 4; ++m)
                aF[m] = *reinterpret_cast<const short8*>(
                    &lds[WOFF + slot * WSL + (wr * 64 + m * 16 + lr) * 64 + swz]);
            #pragma unroll
            for (int n = 0; n < 4; ++n) {
                const int rB = wc * 64 + n * 16 + lr + kt;
                bF[n] = *reinterpret_cast<const short8*>(
                    &lds[xoff + rB * 64 + ((lg ^ ((rB >> 1) & 3)) << 4)]);
            }

            // 2) stage issues (slice g+2 into slot (g+2)%3; X parts @ kt 0,1)
            if (kt == 0) {
                stageW(mod3(s0 + 2), 2, ks * 32);
                if (more) stageX1(par ^ 1, i0n, wv);
            } else if (kt == 1) {
                stageW(mod3(s0 + 3), 3, ks * 32);
                if (more) { stageX1(par ^ 1, i0n, wv + 4);
                            if (wv == 0) stageX1(par ^ 1, i0n, 8); }
            } else if (kt == 2) {
                stageW(mod3(s0 + 4), 4, ks * 32);
            } else if (kt == 3) {
                if (more) stageW(mod3(s0 + 5), 0, i0n);
            } else {
                if (more) stageW(mod3(s0 + 6), 1, i0n);
            }

            // 3) counted vmcnt: keep own-phase issues in flight, force older
            if (kt == 0) {
                if (more) asm volatile("s_waitcnt vmcnt(3)" ::: "memory");
                else      asm volatile("s_waitcnt vmcnt(2)" ::: "memory");
            } else if (kt == 1) {
                if (more) {
                    if (wv == 0) asm volatile("s_waitcnt vmcnt(4)" ::: "memory");
                    else         asm volatile("s_waitcnt vmcnt(3)" ::: "memory");
                } else           asm volatile("s_waitcnt vmcnt(2)" ::: "memory");
            } else if (kt == 2) {
                asm volatile("s_waitcnt vmcnt(2)" ::: "memory");
            } else {
                if (more) asm volatile("s_waitcnt vmcnt(2)" ::: "memory");
                else      asm volatile("s_waitcnt vmcnt(0)" ::: "memory");
            }
            __builtin_amdgcn_s_barrier();

            // 4) MFMA cluster (compiler inserts counted lgkmcnt for aF/bF)
            __builtin_amdgcn_s_setprio(1);
            #pragma unroll
            for (int m = 0; m < 4; ++m)
                #pragma unroll
                for (int n = 0; n < 4; ++n)
                    acc[m][n] = __builtin_amdgcn_mfma_f32_16x16x32_bf16(
                        aF[m], bF[n], acc[m][n], 0, 0, 0);
            __builtin_amdgcn_s_setprio(0);
            __builtin_amdgcn_s_barrier();
        }
        s0 += 2; if (s0 >= 3) s0 -= 3;
    }

    // epilogue: C layout col(l)=lane&15, row(e)=(lane>>4)*4+q
    float spn[4] = {0.f, 0.f, 0.f, 0.f};
    #pragma unroll
    for (int m = 0; m < 4; ++m)
        #pragma unroll
        for (int q = 0; q < 4; ++q) {
            int e = e0 + wr * 64 + m * 16 + lg * 4 + q;
            float bv = bias[e];
            float wv_s = sw[e];
            unsigned short* yr =
                y + ((size_t)b * E_DIM + e) * L2P + l0 + wc * 64 + lr;
            #pragma unroll
            for (int n = 0; n < 4; ++n) {
                float v = acc[m][n][q] + bv;
                yr[n * 16] = f2bf(v);
                spn[n] = fmaf(v, wv_s, spn[n]);
            }
        }
    // reduce score partials over lg (lanes differing in bits 4,5)
    #pragma unroll
    for (int n = 0; n < 4; ++n) {
        float p = spn[n];
        p += __shfl_xor(p, 16);
        p += __shfl_xor(p, 32);
        if (lane < 16) {
            int l = l0 + wc * 64 + n * 16 + lane;
            sp[((size_t)b * L2P + l) * 8 + blockIdx.y * 2 + wr] = p;
        }
    }
}

// ---------------------------------------------------------------------------
// Kernel 2: fold score partials + per-position softmax weights over widths.
// ---------------------------------------------------------------------------
__global__ __launch_bounds__(256)
void weight_kernel(const float* __restrict__ sp, float* __restrict__ A)
{
    const int b  = blockIdx.y;
    const int l0 = blockIdx.x * 256;
    const int tid = threadIdx.x;
    __shared__ float sl[260];

    for (int idx = tid; idx < 260; idx += 256) {
        int l = l0 - 2 + idx;
        float v = 0.f;
        if (l >= 0 && l < L_OUT) {
            const float* p = &sp[((size_t)b * L2P + l) * 8];
            v = ((p[0] + p[1]) + (p[2] + p[3])) + ((p[4] + p[5]) + (p[6] + p[7]));
        }
        sl[idx] = v;
    }
    __syncthreads();

    const int l = l0 + tid;
    if (l >= L_OUT) return;
    #define SL(i) sl[(i) - (l0 - 2)]
    float sc0 = SL(l);
    int n2 = l & ~1;
    float sc1 = 0.5f * (SL(n2) + SL(n2 + 1));
    int n3 = (l / 3) * 3;
    float sc2 = (1.f / 3.f) * (SL(n3) + SL(n3 + 1) + SL(n3 + 2));
    int n4 = l & ~3;
    float sc3 = 0.25f * (SL(n4) + SL(n4 + 1) + SL(n4 + 2) + SL(n4 + 3));
    #undef SL

    float m  = fmaxf(fmaxf(sc0, sc1), fmaxf(sc2, sc3));
    float e0 = __expf(sc0 - m), e1 = __expf(sc1 - m);
    float e2 = __expf(sc2 - m), e3 = __expf(sc3 - m);
    float inv = 1.f / (e0 + e1 + e2 + e3);

    float4 av = make_float4(e0 * inv, e1 * inv, e2 * inv, e3 * inv);
    *reinterpret_cast<float4*>(&A[((size_t)b * L2P + l) * 4]) = av;
}

// ---------------------------------------------------------------------------
// Kernel 3: softmax-weighted combine + downsample-by-2 average.
// ---------------------------------------------------------------------------
typedef __attribute__((ext_vector_type(8))) unsigned short u16x8;

__global__ __launch_bounds__(256)
void combine_kernel(const unsigned short* __restrict__ y,
                    const float* __restrict__ A, float* __restrict__ out)
{
    const int e = blockIdx.x;
    const int b = blockIdx.y;
    const int tid = threadIdx.x;
    __shared__ float ys[L2P];

    const unsigned short* yrow = y + ((size_t)b * E_DIM + e) * L2P;
    #pragma unroll
    for (int j = 0; j < 2; ++j) {
        int base = (tid + j * 256) * 8;
        u16x8 v = *reinterpret_cast<const u16x8*>(&yrow[base]);
        #pragma unroll
        for (int t = 0; t < 8; ++t) ys[base + t] = bf2f(v[t]);
    }
    __syncthreads();

    const float* Ab = A + (size_t)b * L2P * 4;
    float* orow = out + ((size_t)b * E_DIM + e) * L_DS;
    #pragma unroll
    for (int j = 0; j < 8; ++j) {
        int m = tid + j * 256;
        float acc = 0.f;
        #pragma unroll
        for (int r = 0; r < 2; ++r) {
            int l = 2 * m + r;
            if (l < L_OUT) {
                const float4 a4 = *reinterpret_cast<const float4*>(&Ab[l * 4]);
                float t = a4.x * ys[l];
                int n2 = l & ~1;
                t += a4.y * 0.5f * (ys[n2] + ys[n2 + 1]);
                int n3 = (l / 3) * 3;
                t += a4.z * (1.f / 3.f) * (ys[n3] + ys[n3 + 1] + ys[n3 + 2]);
                int n4 = l & ~3;
                t += a4.w * 0.25f * (ys[n4] + ys[n4 + 1] + ys[n4 + 2] + ys[n4 + 3]);
                acc += t;
            }
        }
        orow[m] = 0.5f * acc;
    }
}

// ---------------------------------------------------------------------------
// Workspace layout:
//   Y  : B*E*L2P bf16            = 32 MB     conv output
//   SP : B*L2P*8 f32             =  1 MB     score partials (deterministic)
//   A  : B*L2P*4 f32             = 0.5 MB    softmax weights
//   Xt : B*LP*E bf16             = 32.5 MB   transposed x
//   Wt : 5*E*E bf16              =  2.6 MB
// total ~68.6 MB
// ---------------------------------------------------------------------------
extern "C" void kernel_launch(void* const* d_in, const int* in_sizes, int n_in,
                              void* d_out, int out_size, void* d_ws, size_t ws_size,
                              hipStream_t stream)
{
    const float* x  = (const float*)d_in[0];
    const float* w  = (const float*)d_in[1];
    const float* bb = (const float*)d_in[2];
    const float* sw = (const float*)d_in[3];
    float* out = (float*)d_out;

    unsigned short* Y = (unsigned short*)d_ws;
    float* SP = (float*)(Y + (size_t)B_DIM * E_DIM * L2P);
    float* A  = SP + (size_t)B_DIM * L2P * 8;
    unsigned short* Xt = (unsigned short*)(A + (size_t)B_DIM * L2P * 4);
    unsigned short* Wt = Xt + (size_t)B_DIM * LP * E_DIM;

    xt_kernel<<<dim3(LP / 64, E_DIM / 64, B_DIM), 256, 0, stream>>>(x, Xt);
    wt_kernel<<<dim3(E_DIM * E_DIM / 256), 256, 0, stream>>>(w, Wt);
    conv_mfma<<<dim3(L2P / 128, E_DIM / 128, B_DIM), 256, 0, stream>>>(Xt, Wt, bb, sw, Y, SP);
    weight_kernel<<<dim3(L2P / 256, B_DIM), 256, 0, stream>>>(SP, A);
    combine_kernel<<<dim3(E_DIM, B_DIM), 256, 0, stream>>>(Y, A, out);
}

// Round 13
// 116.463 us; speedup vs baseline: 1.0817x; 1.0817x over previous
//
#include <hip/hip_runtime.h>
#include <stdint.h>

#define E_DIM 512
#define L_IN  4096
#define L_OUT 4092   // L_IN - KW + 1
#define KW    5
#define B_DIM 8
#define L2P   4096   // padded row stride for y workspace
#define L_DS  2048   // downsampled output length
#define LP    4160   // padded length for transposed x

typedef __attribute__((ext_vector_type(8))) short short8;
typedef __attribute__((ext_vector_type(4))) float f32x4;

__device__ __forceinline__ unsigned short f2bf(float f) {
    uint32_t u = __float_as_uint(f);
    u += 0x7fffu + ((u >> 16) & 1);   // round-to-nearest-even
    return (unsigned short)(u >> 16);
}
__device__ __forceinline__ float bf2f(unsigned short h) {
    return __uint_as_float((uint32_t)h << 16);
}

// ---------------------------------------------------------------------------
// Converter 1: x [B][E][4096] f32 -> Xt [B][LP][E] bf16 (transposed; l-rows
// >= 4096 zeroed). f32 LDS tile [64][65] (2-way banks = free).
// ---------------------------------------------------------------------------
__global__ __launch_bounds__(256)
void xt_kernel(const float* __restrict__ x, unsigned short* __restrict__ Xt)
{
    const int b  = blockIdx.z;
    const int i0 = blockIdx.y * 64;
    const int l0 = blockIdx.x * 64;
    __shared__ float T[64][65];
    const int tid = threadIdx.x;

    const int ir = tid >> 4;          // 0..15
    const int cq = (tid & 15) * 4;    // 0..60
    #pragma unroll
    for (int jj = 0; jj < 4; ++jj) {
        int i = jj * 16 + ir;
        float4 v = make_float4(0.f, 0.f, 0.f, 0.f);
        if (l0 < L_IN)
            v = *reinterpret_cast<const float4*>(
                &x[((size_t)b * E_DIM + i0 + i) * L_IN + l0 + cq]);
        T[i][cq + 0] = v.x; T[i][cq + 1] = v.y;
        T[i][cq + 2] = v.z; T[i][cq + 3] = v.w;
    }
    __syncthreads();
    const int h  = tid & 31;          // i-pair
    const int rq = tid >> 5;          // 0..7
    #pragma unroll
    for (int j = 0; j < 8; ++j) {
        int lr = j * 8 + rq;
        ushort2 o;
        o.x = f2bf(T[2 * h][lr]);
        o.y = f2bf(T[2 * h + 1][lr]);
        *reinterpret_cast<ushort2*>(
            &Xt[((size_t)b * LP + l0 + lr) * E_DIM + i0 + 2 * h]) = o;
    }
}

// ---------------------------------------------------------------------------
// Converter 2: w [E][E][5] f32 -> Wt [5][E][E] bf16  (Wt[k][e][i] = w[e][i][k])
// ---------------------------------------------------------------------------
__global__ __launch_bounds__(256)
void wt_kernel(const float* __restrict__ w, unsigned short* __restrict__ Wt)
{
    int idx = blockIdx.x * 256 + threadIdx.x;   // e*512 + i
    if (idx >= E_DIM * E_DIM) return;
    #pragma unroll
    for (int k = 0; k < KW; ++k)
        Wt[(size_t)k * E_DIM * E_DIM + idx] = f2bf(w[(size_t)idx * KW + k]);
}

// ---------------------------------------------------------------------------
// Kernel 1: implicit-GEMM conv via MFMA (+ fused score partials).
// y[b,e,l] = sum_k sum_i Wt[k][e][i] * Xt[b][l+k][i] + bias[e]   (bf16 out)
// Block: 128(e) x 256(l), 4 waves (2x2), each wave 64e x 128l = 4x8 frags.
// R7 structure — the measured family optimum (conv 77.0 us), sitting on the
// ds_read_b128 throughput roofline: 3.93M b128 x 12cyc / 256CU / 2.4GHz
// = 76.8 us. 2-barrier K-loop; per-wave tap rotation; XOR swizzle
// f(row)=(row>>1)&3 on the 16B slot (bank-conflict-free, verified 0).
// ---------------------------------------------------------------------------
#define XS_ROWS  272                         // 256 l + 4 taps, rounded to 16
#define XS_BYTES (XS_ROWS * 64)              // 17408
#define N_XCH    (XS_BYTES / 1024)           // 17 chunks
#define WS_OFF   XS_BYTES
#define WS_BYTES (5 * 128 * 64)              // 40960
#define LDS_BYTES (XS_BYTES + WS_BYTES)      // 58368
#define N_CH     (LDS_BYTES / 1024)          // 57 chunks

__global__ __launch_bounds__(256, 2)
void conv_mfma(const unsigned short* __restrict__ Xt,
               const unsigned short* __restrict__ Wt,
               const float* __restrict__ bias,
               const float* __restrict__ sw,
               unsigned short* __restrict__ y,
               float* __restrict__ sp)
{
    __shared__ __align__(16) unsigned char lds[LDS_BYTES];
    const int l0 = blockIdx.x * 256;
    const int e0 = blockIdx.y * 128;
    const int b  = blockIdx.z;
    const int tid  = threadIdx.x;
    const int lane = tid & 63;
    const int wv   = tid >> 6;
    const int wr = wv >> 1, wc = wv & 1;      // e-half / l-half
    const int lr = lane & 15, lg = lane >> 4; // frag row / k-group
    const int ln4r = lane >> 2;               // row within 1KB chunk
    // stage-side source-column swizzle (lane-constant)
    const int xswz = ((lane & 3) ^ ((lane >> 3) & 3)) * 8;

    const unsigned short* xt_base =
        Xt + ((size_t)b * LP + l0) * E_DIM + xswz;

    f32x4 acc[4][8] = {};

    for (int ks = 0; ks < 16; ++ks) {
        const int i0 = ks * 32;
        __syncthreads();
        for (int cch = wv; cch < N_CH; cch += 4) {
            void* lp = (void*)(lds + cch * 1024);
            const unsigned short* gp;
            if (cch < N_XCH) {
                int row = cch * 16 + ln4r;                 // l_rel in [0,272)
                gp = xt_base + (size_t)row * E_DIM + i0;
            } else {
                int rk = (cch - N_XCH) * 16 + ln4r;        // k*128 + e_rel
                int k = rk >> 7, er = rk & 127;
                gp = Wt + ((size_t)k * E_DIM + e0 + er) * E_DIM + i0 + xswz;
            }
            __builtin_amdgcn_global_load_lds(
                (const __attribute__((address_space(1))) void*)gp,
                (__attribute__((address_space(3))) void*)lp,
                16, 0, 0);
        }
        __syncthreads();

        // tap loop, rotated per wave: wave wv processes taps wv, wv+1, ... mod 5
        #pragma unroll
        for (int j = 0; j < KW; ++j) {
            int kt = j + wv; if (kt >= KW) kt -= KW;
            const int aAddr = WS_OFF + (kt * 128 + wr * 64 + lr) * 64
                            + ((lg ^ ((lr >> 1) & 3)) << 4);
            const int rB = wc * 128 + lr + kt;
            const int bAddr = rB * 64 + ((lg ^ (((lr + kt) >> 1) & 3)) << 4);

            short8 aF[4], bF[8];
            #pragma unroll
            for (int m = 0; m < 4; ++m)
                aF[m] = *reinterpret_cast<const short8*>(&lds[aAddr + m * 1024]);
            #pragma unroll
            for (int n = 0; n < 8; ++n)
                bF[n] = *reinterpret_cast<const short8*>(&lds[bAddr + n * 1024]);
            #pragma unroll
            for (int m = 0; m < 4; ++m)
                #pragma unroll
                for (int n = 0; n < 8; ++n)
                    acc[m][n] = __builtin_amdgcn_mfma_f32_16x16x32_bf16(
                        aF[m], bF[n], acc[m][n], 0, 0, 0);
        }
    }

    // epilogue: C layout col(l)=lane&15, row(e)=(lane>>4)*4+q
    float spn[8] = {};
    #pragma unroll
    for (int m = 0; m < 4; ++m)
        #pragma unroll
        for (int q = 0; q < 4; ++q) {
            int e = e0 + wr * 64 + m * 16 + lg * 4 + q;
            float bv = bias[e];
            float wv_s = sw[e];
            unsigned short* yr =
                y + ((size_t)b * E_DIM + e) * L2P + l0 + wc * 128 + lr;
            #pragma unroll
            for (int n = 0; n < 8; ++n) {
                float v = acc[m][n][q] + bv;
                yr[n * 16] = f2bf(v);
                spn[n] = fmaf(v, wv_s, spn[n]);
            }
        }
    // reduce score partials over lg (lanes differing in bits 4,5)
    #pragma unroll
    for (int n = 0; n < 8; ++n) {
        float p = spn[n];
        p += __shfl_xor(p, 16);
        p += __shfl_xor(p, 32);
        if (lane < 16) {
            int l = l0 + wc * 128 + n * 16 + lane;
            sp[((size_t)b * L2P + l) * 8 + blockIdx.y * 2 + wr] = p;
        }
    }
}

// ---------------------------------------------------------------------------
// Kernel 2: fold score partials + per-position softmax weights over widths.
// ---------------------------------------------------------------------------
__global__ __launch_bounds__(256)
void weight_kernel(const float* __restrict__ sp, float* __restrict__ A)
{
    const int b  = blockIdx.y;
    const int l0 = blockIdx.x * 256;
    const int tid = threadIdx.x;
    __shared__ float sl[260];

    for (int idx = tid; idx < 260; idx += 256) {
        int l = l0 - 2 + idx;
        float v = 0.f;
        if (l >= 0 && l < L_OUT) {
            const float* p = &sp[((size_t)b * L2P + l) * 8];
            v = ((p[0] + p[1]) + (p[2] + p[3])) + ((p[4] + p[5]) + (p[6] + p[7]));
        }
        sl[idx] = v;
    }
    __syncthreads();

    const int l = l0 + tid;
    if (l >= L_OUT) return;
    #define SL(i) sl[(i) - (l0 - 2)]
    float sc0 = SL(l);
    int n2 = l & ~1;
    float sc1 = 0.5f * (SL(n2) + SL(n2 + 1));
    int n3 = (l / 3) * 3;
    float sc2 = (1.f / 3.f) * (SL(n3) + SL(n3 + 1) + SL(n3 + 2));
    int n4 = l & ~3;
    float sc3 = 0.25f * (SL(n4) + SL(n4 + 1) + SL(n4 + 2) + SL(n4 + 3));
    #undef SL

    float m  = fmaxf(fmaxf(sc0, sc1), fmaxf(sc2, sc3));
    float e0 = __expf(sc0 - m), e1 = __expf(sc1 - m);
    float e2 = __expf(sc2 - m), e3 = __expf(sc3 - m);
    float inv = 1.f / (e0 + e1 + e2 + e3);

    float4 av = make_float4(e0 * inv, e1 * inv, e2 * inv, e3 * inv);
    *reinterpret_cast<float4*>(&A[((size_t)b * L2P + l) * 4]) = av;
}

// ---------------------------------------------------------------------------
// Kernel 3: softmax-weighted combine + downsample-by-2 average.
// ---------------------------------------------------------------------------
typedef __attribute__((ext_vector_type(8))) unsigned short u16x8;

__global__ __launch_bounds__(256)
void combine_kernel(const unsigned short* __restrict__ y,
                    const float* __restrict__ A, float* __restrict__ out)
{
    const int e = blockIdx.x;
    const int b = blockIdx.y;
    const int tid = threadIdx.x;
    __shared__ float ys[L2P];

    const unsigned short* yrow = y + ((size_t)b * E_DIM + e) * L2P;
    #pragma unroll
    for (int j = 0; j < 2; ++j) {
        int base = (tid + j * 256) * 8;
        u16x8 v = *reinterpret_cast<const u16x8*>(&yrow[base]);
        #pragma unroll
        for (int t = 0; t < 8; ++t) ys[base + t] = bf2f(v[t]);
    }
    __syncthreads();

    const float* Ab = A + (size_t)b * L2P * 4;
    float* orow = out + ((size_t)b * E_DIM + e) * L_DS;
    #pragma unroll
    for (int j = 0; j < 8; ++j) {
        int m = tid + j * 256;
        float acc = 0.f;
        #pragma unroll
        for (int r = 0; r < 2; ++r) {
            int l = 2 * m + r;
            if (l < L_OUT) {
                const float4 a4 = *reinterpret_cast<const float4*>(&Ab[l * 4]);
                float t = a4.x * ys[l];
                int n2 = l & ~1;
                t += a4.y * 0.5f * (ys[n2] + ys[n2 + 1]);
                int n3 = (l / 3) * 3;
                t += a4.z * (1.f / 3.f) * (ys[n3] + ys[n3 + 1] + ys[n3 + 2]);
                int n4 = l & ~3;
                t += a4.w * 0.25f * (ys[n4] + ys[n4 + 1] + ys[n4 + 2] + ys[n4 + 3]);
                acc += t;
            }
        }
        orow[m] = 0.5f * acc;
    }
}

// ---------------------------------------------------------------------------
// Workspace layout:
//   Y  : B*E*L2P bf16            = 32 MB     conv output
//   SP : B*L2P*8 f32             =  1 MB     score partials (deterministic)
//   A  : B*L2P*4 f32             = 0.5 MB    softmax weights
//   Xt : B*LP*E bf16             = 32.5 MB   transposed x
//   Wt : 5*E*E bf16              =  2.6 MB
// total ~68.6 MB
// ---------------------------------------------------------------------------
extern "C" void kernel_launch(void* const* d_in, const int* in_sizes, int n_in,
                              void* d_out, int out_size, void* d_ws, size_t ws_size,
                              hipStream_t stream)
{
    const float* x  = (const float*)d_in[0];
    const float* w  = (const float*)d_in[1];
    const float* bb = (const float*)d_in[2];
    const float* sw = (const float*)d_in[3];
    float* out = (float*)d_out;

    unsigned short* Y = (unsigned short*)d_ws;
    float* SP = (float*)(Y + (size_t)B_DIM * E_DIM * L2P);
    float* A  = SP + (size_t)B_DIM * L2P * 8;
    unsigned short* Xt = (unsigned short*)(A + (size_t)B_DIM * L2P * 4);
    unsigned short* Wt = Xt + (size_t)B_DIM * LP * E_DIM;

    xt_kernel<<<dim3(LP / 64, E_DIM / 64, B_DIM), 256, 0, stream>>>(x, Xt);
    wt_kernel<<<dim3(E_DIM * E_DIM / 256), 256, 0, stream>>>(w, Wt);
    conv_mfma<<<dim3(L2P / 256, E_DIM / 128, B_DIM), 256, 0, stream>>>(Xt, Wt, bb, sw, Y, SP);
    weight_kernel<<<dim3(L2P / 256, B_DIM), 256, 0, stream>>>(SP, A);
    combine_kernel<<<dim3(E_DIM, B_DIM), 256, 0, stream>>>(Y, A, out);
}